// Round 2
// baseline (258.697 us; speedup 1.0000x reference)
//
#include <hip/hip_runtime.h>

#define BS 8
#define NN 256
#define GD 64
#define ND 64
#define ED 32

// K2 tiling
#define JC 8     // j's per block
#define IB 64    // i's per block (4 splits)

// ---------------------------------------------------------------------------
// K1: vj_proj[b,n,o] = V[b,n,:]@Wa_vj[:,o] ; vi_proj[b,n,o] = V[b,n,:]@Wa_vi[:,o]
//     u_projA[b,o]   = u[b,:]@Wa_u[:,o] + b_A[o]
// grid = BS*NN blocks, 64 threads
// ---------------------------------------------------------------------------
__global__ void k1_proj(const float* __restrict__ u, const float* __restrict__ V,
                        const float* __restrict__ W_A, const float* __restrict__ b_A,
                        float* __restrict__ vj, float* __restrict__ vi,
                        float* __restrict__ up) {
    int bn = blockIdx.x;               // 0..BS*NN-1
    int b  = bn >> 8;
    int n  = bn & (NN - 1);
    int t  = threadIdx.x;              // 0..63
    __shared__ float vrow[ND];
    vrow[t] = V[bn * ND + t];
    __syncthreads();
    int o = t & 31;
    // rows ED.. for vj, rows ED+ND.. for vi
    const float* Wbase = W_A + (t < 32 ? ED * ED : (ED + ND) * ED);
    float d0 = 0.f, d1 = 0.f, d2 = 0.f, d3 = 0.f;
#pragma unroll
    for (int k = 0; k < ND; k += 4) {
        d0 = fmaf(vrow[k + 0], Wbase[(k + 0) * ED + o], d0);
        d1 = fmaf(vrow[k + 1], Wbase[(k + 1) * ED + o], d1);
        d2 = fmaf(vrow[k + 2], Wbase[(k + 2) * ED + o], d2);
        d3 = fmaf(vrow[k + 3], Wbase[(k + 3) * ED + o], d3);
    }
    float acc = (d0 + d1) + (d2 + d3);
    if (t < 32) vj[bn * ED + o] = acc;
    else        vi[bn * ED + o] = acc;

    if (n == 0 && t < 32) {
        float a2 = b_A[t];
#pragma unroll
        for (int k = 0; k < GD; ++k)
            a2 = fmaf(u[b * GD + k], W_A[(ED + 2 * ND + k) * ED + t], a2);
        up[b * ED + t] = a2;
    }
}

// ---------------------------------------------------------------------------
// K2: A_prime[b,i,j,o] = relu(A[b,i,j,:]@Wa_e[:,o] + vj[b,j,o] + vi[b,i,o] + up[b,o])
//     parts[ih,b,j,o]  = sum over the block's 64 i's of A_prime
// grid = BS * (NN/JC) * (NN/IB) = 8*32*4 = 1024 blocks, 256 threads
// thread t -> (jloc = t>>5, o = t&31); W column held in 32 VGPRs
// ---------------------------------------------------------------------------
__global__ __launch_bounds__(256) void k2_main(
        const float* __restrict__ A, const float* __restrict__ W_A,
        const float* __restrict__ vj, const float* __restrict__ vi,
        const float* __restrict__ up,
        float* __restrict__ Aprime, float* __restrict__ parts) {
    int bid = blockIdx.x;
    int b   = bid >> 7;           // /128
    int jc  = (bid >> 2) & 31;
    int ih  = bid & 3;
    int t    = threadIdx.x;
    int jloc = t >> 5;
    int o    = t & 31;
    int j    = jc * JC + jloc;

    float w[ED];
#pragma unroll
    for (int e = 0; e < ED; ++e) w[e] = W_A[e * ED + o];

    float cj = vj[(b * NN + j) * ED + o] + up[b * ED + o];
    float colacc = 0.f;

    int i0 = ih * IB;
    const float* Ab  = A      + ((size_t)((b * NN + i0) * NN + j)) * ED;
    float*       Pb  = Aprime + ((size_t)((b * NN + i0) * NN + j)) * ED;
    const float* vib = vi + ((b * NN + i0) * ED) + o;

    for (int ii = 0; ii < IB; ++ii) {
        const float4* ap = reinterpret_cast<const float4*>(Ab + (size_t)ii * (NN * ED));
        float areg[ED];
#pragma unroll
        for (int q = 0; q < 8; ++q) {
            float4 f = ap[q];
            areg[4 * q + 0] = f.x; areg[4 * q + 1] = f.y;
            areg[4 * q + 2] = f.z; areg[4 * q + 3] = f.w;
        }
        float viv = vib[ii * ED];
        float d0 = 0.f, d1 = 0.f, d2 = 0.f, d3 = 0.f;
#pragma unroll
        for (int e = 0; e < ED; e += 4) {
            d0 = fmaf(areg[e + 0], w[e + 0], d0);
            d1 = fmaf(areg[e + 1], w[e + 1], d1);
            d2 = fmaf(areg[e + 2], w[e + 2], d2);
            d3 = fmaf(areg[e + 3], w[e + 3], d3);
        }
        float v = (d0 + d1) + (d2 + d3) + cj + viv;
        v = fmaxf(v, 0.f);
        Pb[(size_t)ii * (NN * ED) + o] = v;
        colacc += v;
    }
    parts[(((ih * BS + b) * NN + j) * ED) + o] = colacc;
}

// ---------------------------------------------------------------------------
// K3: V_prime[b,n,d] = relu([colsum/256, V, u] @ W_v + b_v)
// grid = BS*NN/4 blocks, 256 threads; 4 rows per block
// ---------------------------------------------------------------------------
__global__ __launch_bounds__(256) void k3_vprime(
        const float* __restrict__ V, const float* __restrict__ u,
        const float* __restrict__ W_v, const float* __restrict__ b_v,
        const float* __restrict__ parts, float* __restrict__ Vprime) {
    int r0 = blockIdx.x * 4;
    int t  = threadIdx.x;
    int rl = t >> 6;           // 0..3
    int d  = t & 63;
    int bn = r0 + rl;
    int b  = bn >> 8;
    int n  = bn & (NN - 1);
    __shared__ float xv[4][ED + ND + GD + 1];   // 160 + pad
    if (d < 32) {
        float s = 0.f;
#pragma unroll
        for (int ih = 0; ih < 4; ++ih)
            s += parts[((ih * BS + b) * NN + n) * ED + d];
        xv[rl][d] = s * (1.f / 256.f);
    }
    xv[rl][ED + d]      = V[bn * ND + d];
    xv[rl][ED + ND + d] = u[b * GD + d];
    __syncthreads();
    float acc = b_v[d];
#pragma unroll 8
    for (int k = 0; k < ED + ND + GD; ++k)
        acc = fmaf(xv[rl][k], W_v[k * ND + d], acc);
    Vprime[bn * ND + d] = fmaxf(acc, 0.f);
}

// ---------------------------------------------------------------------------
// K4: A_agg, v_agg, u_prime. grid = BS blocks, 64 threads
// ---------------------------------------------------------------------------
__global__ void k4_uprime(const float* __restrict__ u,
                          const float* __restrict__ W_u, const float* __restrict__ b_u,
                          const float* __restrict__ parts, const float* __restrict__ Vprime,
                          float* __restrict__ uprime) {
    int b = blockIdx.x;
    int t = threadIdx.x;       // 0..63
    __shared__ float xu[ED + ND + GD];
    // v_agg
    {
        float s0 = 0.f, s1 = 0.f, s2 = 0.f, s3 = 0.f;
        for (int n = 0; n < NN; n += 4) {
            s0 += Vprime[(b * NN + n + 0) * ND + t];
            s1 += Vprime[(b * NN + n + 1) * ND + t];
            s2 += Vprime[(b * NN + n + 2) * ND + t];
            s3 += Vprime[(b * NN + n + 3) * ND + t];
        }
        xu[ED + t] = ((s0 + s1) + (s2 + s3)) * (1.f / 256.f);
    }
    // A_agg
    if (t < 32) {
        float s0 = 0.f, s1 = 0.f, s2 = 0.f, s3 = 0.f;
        for (int jj = 0; jj < NN; ++jj) {
            s0 += parts[((0 * BS + b) * NN + jj) * ED + t];
            s1 += parts[((1 * BS + b) * NN + jj) * ED + t];
            s2 += parts[((2 * BS + b) * NN + jj) * ED + t];
            s3 += parts[((3 * BS + b) * NN + jj) * ED + t];
        }
        xu[t] = ((s0 + s1) + (s2 + s3)) * (1.f / 65536.f);
    }
    xu[ED + ND + t] = u[b * GD + t];
    __syncthreads();
    float acc = b_u[t];
#pragma unroll 8
    for (int k = 0; k < ED + ND + GD; ++k)
        acc = fmaf(xu[k], W_u[k * GD + t], acc);
    uprime[b * GD + t] = fmaxf(acc, 0.f);
}

// ---------------------------------------------------------------------------
extern "C" void kernel_launch(void* const* d_in, const int* in_sizes, int n_in,
                              void* d_out, int out_size, void* d_ws, size_t ws_size,
                              hipStream_t stream) {
    const float* u   = (const float*)d_in[0];
    const float* V   = (const float*)d_in[1];
    const float* A   = (const float*)d_in[2];
    const float* W_A = (const float*)d_in[3];
    const float* b_A = (const float*)d_in[4];
    const float* W_v = (const float*)d_in[5];
    const float* b_v = (const float*)d_in[6];
    const float* W_u = (const float*)d_in[7];
    const float* b_u = (const float*)d_in[8];

    float* out    = (float*)d_out;
    float* uprime = out;                           // 8*64
    float* Vprime = out + BS * GD;                 // 8*256*64
    float* Aprime = out + BS * GD + BS * NN * ND;  // 8*256*256*32

    float* ws    = (float*)d_ws;
    float* vj    = ws;                                   // BS*NN*ED
    float* vi    = ws + BS * NN * ED;                    // BS*NN*ED
    float* up    = ws + 2 * BS * NN * ED;                // BS*ED
    float* parts = ws + 2 * BS * NN * ED + BS * ED;      // 4*BS*NN*ED

    hipLaunchKernelGGL(k1_proj, dim3(BS * NN), dim3(64), 0, stream,
                       u, V, W_A, b_A, vj, vi, up);
    hipLaunchKernelGGL(k2_main, dim3(BS * (NN / JC) * (NN / IB)), dim3(256), 0, stream,
                       A, W_A, vj, vi, up, Aprime, parts);
    hipLaunchKernelGGL(k3_vprime, dim3(BS * NN / 4), dim3(256), 0, stream,
                       V, u, W_v, b_v, parts, Vprime);
    hipLaunchKernelGGL(k4_uprime, dim3(BS), dim3(64), 0, stream,
                       u, W_u, b_u, parts, Vprime, uprime);
}

// Round 6
// 186.306 us; speedup vs baseline: 1.3886x; 1.3886x over previous
//
#include <hip/hip_runtime.h>
#include <stdint.h>

#define BS 8
#define NN 256
#define GD 64
#define ND 64
#define ED 32

#define GLOBAL_AS __attribute__((address_space(1)))
#define LDS_AS    __attribute__((address_space(3)))

// ---------------------------------------------------------------------------
// K1: vj[b,n,o] = V[b,n,:]@Wa_vj[:,o] ; vi[b,n,o] = V[b,n,:]@Wa_vi[:,o]
//     up[b,o]   = u[b,:]@Wa_u[:,o] + b_A[o] ;  also zeroes colsum (ws poisoned)
// grid = 64 blocks x 256 thr; 32 V-rows per block; W_vj|W_vi staged in LDS
// ---------------------------------------------------------------------------
__global__ __launch_bounds__(256) void k1_proj(
        const float* __restrict__ u, const float* __restrict__ V,
        const float* __restrict__ W_A, const float* __restrict__ b_A,
        float* __restrict__ vj, float* __restrict__ vi, float* __restrict__ up,
        float* __restrict__ colsum) {
    __shared__ float W2[2 * ND][ED];   // 16KB: W_A rows ED..ED+127
    __shared__ float Vt[32][ND];       // 8KB
    int t   = threadIdx.x;
    int blk = blockIdx.x;
    int bn0 = blk * 32;
    // zero colsum: 65536 floats over 64 blocks
    {
        float4* cz = (float4*)(colsum + blk * 1024);
        cz[t] = make_float4(0.f, 0.f, 0.f, 0.f);
    }
    {
        const float4* src = (const float4*)(W_A + ED * ED);
        float4* dst = (float4*)&W2[0][0];
#pragma unroll
        for (int r = 0; r < 4; ++r) dst[r * 256 + t] = src[r * 256 + t];
    }
    {
        const float4* src = (const float4*)(V + (size_t)bn0 * ND);
        float4* dst = (float4*)&Vt[0][0];
        dst[t]       = src[t];
        dst[256 + t] = src[256 + t];
    }
    __syncthreads();
    int rq  = t >> 6;          // 0..3
    int oo  = t & 63;
    int mat = oo >> 5;         // 0 = vj, 1 = vi
    int o   = oo & 31;
#pragma unroll 2
    for (int p = 0; p < 8; ++p) {
        int rl = p * 4 + rq;
        int bn = bn0 + rl;
        float d0 = 0.f, d1 = 0.f, d2 = 0.f, d3 = 0.f;
#pragma unroll
        for (int k = 0; k < ND; k += 4) {
            d0 = fmaf(Vt[rl][k + 0], W2[mat * ND + k + 0][o], d0);
            d1 = fmaf(Vt[rl][k + 1], W2[mat * ND + k + 1][o], d1);
            d2 = fmaf(Vt[rl][k + 2], W2[mat * ND + k + 2][o], d2);
            d3 = fmaf(Vt[rl][k + 3], W2[mat * ND + k + 3][o], d3);
        }
        float acc = (d0 + d1) + (d2 + d3);
        if (mat == 0) vj[bn * ED + o] = acc;
        else          vi[bn * ED + o] = acc;
    }
    // up for b = blk (first 8 blocks)
    if (blk < 8 && t < 32) {
        float a2 = b_A[t];
#pragma unroll 8
        for (int k = 0; k < GD; ++k)
            a2 = fmaf(u[blk * GD + k], W_A[(ED + 2 * ND + k) * ED + t], a2);
        up[blk * ED + t] = a2;
    }
}

// ---------------------------------------------------------------------------
// K2: A_prime[b,i,j,o] = relu(A[b,i,j,:]@Wa_e[:,o] + vj[b,j,o] + vi[b,i,o] + up[b,o])
//     colsum[b,j,o] += sum over the block's 16 i's (atomic, 16 adds/addr)
// grid = BS*16*32 = 4096 blocks x 256 thr. Tile: 16 i x 8 j.
// A tile staged via global_load_lds width-16 (1KB per wave-instr, coalesced).
// ---------------------------------------------------------------------------
__global__ __launch_bounds__(256) void k2_main(
        const float* __restrict__ A, const float* __restrict__ W_A,
        const float* __restrict__ vj, const float* __restrict__ vi,
        const float* __restrict__ up,
        float* __restrict__ Aprime, float* __restrict__ colsum) {
    __shared__ float tile[16][8][ED];   // 16KB [i][j][e]
    __shared__ float vit[16][ED];       // 2KB
    int bid = blockIdx.x;
    int b   = bid >> 9;            // /512
    int it  = (bid >> 5) & 15;
    int jc  = bid & 31;
    int t    = threadIdx.x;
    int lane = t & 63;
    int wv   = t >> 6;             // wave id 0..3
    int i0 = it * 16;
    int j0 = jc * 8;

    // --- stage A tile: 4 rounds x (4 waves x 1KB) ---
    const float* Asrc = A + ((size_t)(b * NN + i0) * NN + j0) * ED;
#pragma unroll
    for (int r = 0; r < 4; ++r) {
        int il = r * 4 + wv;                       // wave-uniform
        const float* g = Asrc + (size_t)il * NN * ED + lane * 4;
        __builtin_amdgcn_global_load_lds((const GLOBAL_AS void*)g,
                                         (LDS_AS void*)&tile[il][0][0], 16, 0, 0);
    }
    // --- stage vi tile (512 floats) via regs ---
    {
        const float* vsrc = vi + (size_t)(b * NN + i0) * ED;
        ((float*)vit)[t]       = vsrc[t];
        ((float*)vit)[t + 256] = vsrc[t + 256];
    }
    // --- W column into registers (overlaps with staging) ---
    int jloc = t >> 5;
    int o    = t & 31;
    int j    = j0 + jloc;
    float w_[ED];
#pragma unroll
    for (int e = 0; e < ED; ++e) w_[e] = W_A[e * ED + o];
    float cj = vj[(b * NN + j) * ED + o] + up[b * ED + o];

    __syncthreads();

    float colacc = 0.f;
    float* Pb = Aprime + ((size_t)(b * NN + i0) * NN + j) * ED + o;
#pragma unroll 2
    for (int ii = 0; ii < 16; ++ii) {
        const float4* lr = (const float4*)(&tile[ii][jloc][0]);
        float d0 = 0.f, d1 = 0.f, d2 = 0.f, d3 = 0.f;
#pragma unroll
        for (int q = 0; q < 8; ++q) {
            float4 f = lr[q];
            d0 = fmaf(f.x, w_[4 * q + 0], d0);
            d1 = fmaf(f.y, w_[4 * q + 1], d1);
            d2 = fmaf(f.z, w_[4 * q + 2], d2);
            d3 = fmaf(f.w, w_[4 * q + 3], d3);
        }
        float v = (d0 + d1) + (d2 + d3) + cj + vit[ii][o];
        v = fmaxf(v, 0.f);
        Pb[(size_t)ii * NN * ED] = v;
        colacc += v;
    }
    atomicAdd(&colsum[(b * NN + j) * ED + o], colacc);
}

// ---------------------------------------------------------------------------
// K3: V_prime[b,n,d] = relu([colsum/256, V, u] @ W_v + b_v)
// grid = 128 blocks x 256 thr; 16 rows per block; W_v staged in LDS (40KB)
// ---------------------------------------------------------------------------
__global__ __launch_bounds__(256) void k3_vprime(
        const float* __restrict__ V, const float* __restrict__ u,
        const float* __restrict__ W_v, const float* __restrict__ b_v,
        const float* __restrict__ colsum, float* __restrict__ Vprime) {
    __shared__ float Wv[ED + ND + GD][ND];   // 160x64 = 40KB
    __shared__ float xv[16][ED + ND + GD];   // 10KB
    int t = threadIdx.x;
    {
        const float4* src = (const float4*)W_v;
        float4* dst = (float4*)&Wv[0][0];
#pragma unroll
        for (int r = 0; r < 10; ++r) dst[r * 256 + t] = src[r * 256 + t];
    }
    int bn0 = blockIdx.x * 16;
    int d  = t & 63;
    int rq = t >> 6;
#pragma unroll
    for (int p = 0; p < 4; ++p) {
        int rl = p * 4 + rq;
        int bn = bn0 + rl;
        int b  = bn >> 8;
        if (d < 32) xv[rl][d] = colsum[bn * ED + d] * (1.f / 256.f);
        xv[rl][ED + d]      = V[(size_t)bn * ND + d];
        xv[rl][ED + ND + d] = u[b * GD + d];
    }
    __syncthreads();
#pragma unroll 2
    for (int p = 0; p < 4; ++p) {
        int rl = p * 4 + rq;
        int bn = bn0 + rl;
        float acc = b_v[d];
#pragma unroll 8
        for (int k = 0; k < ED + ND + GD; ++k)
            acc = fmaf(xv[rl][k], Wv[k][d], acc);
        Vprime[(size_t)bn * ND + d] = fmaxf(acc, 0.f);
    }
}

// ---------------------------------------------------------------------------
// K4: A_agg (from colsum), v_agg (from Vprime), u_prime. grid = 8 x 256 thr
// ---------------------------------------------------------------------------
__global__ __launch_bounds__(256) void k4_uprime(
        const float* __restrict__ u,
        const float* __restrict__ W_u, const float* __restrict__ b_u,
        const float* __restrict__ colsum, const float* __restrict__ Vprime,
        float* __restrict__ uprime) {
    int b = blockIdx.x;
    int t = threadIdx.x;
    __shared__ float vpart[4][ND];
    __shared__ float apart[8][ED];
    __shared__ float xu[ED + ND + GD];
    {
        int d = t & 63, g = t >> 6;
        float s = 0.f;
        for (int n = g; n < NN; n += 4)
            s += Vprime[(size_t)(b * NN + n) * ND + d];
        vpart[g][d] = s;
    }
    {
        int o = t & 31, g = t >> 5;
        float s = 0.f;
        for (int n = g; n < NN; n += 8)
            s += colsum[(b * NN + n) * ED + o];
        apart[g][o] = s;
    }
    __syncthreads();
    if (t < 32) {
        float s = 0.f;
#pragma unroll
        for (int g = 0; g < 8; ++g) s += apart[g][t];
        xu[t] = s * (1.f / 65536.f);
    }
    if (t < 64) {
        xu[ED + t]      = (vpart[0][t] + vpart[1][t] + vpart[2][t] + vpart[3][t]) * (1.f / 256.f);
        xu[ED + ND + t] = u[b * GD + t];
    }
    __syncthreads();
    if (t < 64) {
        float acc = b_u[t];
#pragma unroll 8
        for (int k = 0; k < ED + ND + GD; ++k)
            acc = fmaf(xu[k], W_u[k * GD + t], acc);
        uprime[b * GD + t] = fmaxf(acc, 0.f);
    }
}

// ---------------------------------------------------------------------------
extern "C" void kernel_launch(void* const* d_in, const int* in_sizes, int n_in,
                              void* d_out, int out_size, void* d_ws, size_t ws_size,
                              hipStream_t stream) {
    const float* u   = (const float*)d_in[0];
    const float* V   = (const float*)d_in[1];
    const float* A   = (const float*)d_in[2];
    const float* W_A = (const float*)d_in[3];
    const float* b_A = (const float*)d_in[4];
    const float* W_v = (const float*)d_in[5];
    const float* b_v = (const float*)d_in[6];
    const float* W_u = (const float*)d_in[7];
    const float* b_u = (const float*)d_in[8];

    float* out    = (float*)d_out;
    float* uprime = out;                           // 8*64
    float* Vprime = out + BS * GD;                 // 8*256*64
    float* Aprime = out + BS * GD + BS * NN * ND;  // 8*256*256*32

    float* ws     = (float*)d_ws;
    float* vj     = ws;                                    // BS*NN*ED (256KB)
    float* vi     = vj + BS * NN * ED;                     // BS*NN*ED (256KB)
    float* up     = vi + BS * NN * ED;                     // BS*ED
    float* colsum = up + BS * ED;                          // BS*NN*ED (256KB)

    hipLaunchKernelGGL(k1_proj, dim3(64), dim3(256), 0, stream,
                       u, V, W_A, b_A, vj, vi, up, colsum);
    hipLaunchKernelGGL(k2_main, dim3(BS * 16 * 32), dim3(256), 0, stream,
                       A, W_A, vj, vi, up, Aprime, colsum);
    hipLaunchKernelGGL(k3_vprime, dim3(128), dim3(256), 0, stream,
                       V, u, W_v, b_v, colsum, Vprime);
    hipLaunchKernelGGL(k4_uprime, dim3(BS), dim3(256), 0, stream,
                       u, W_u, b_u, colsum, Vprime, uprime);
}